// Round 4
// baseline (118.698 us; speedup 1.0000x reference)
//
#include <hip/hip_runtime.h>
#include <math.h>

#define NHEAD 8
#define HEAD_DIM 32
#define IMG_H 32
#define IMG_W 40
#define NPIX (IMG_H*IMG_W)
#define CMAX 160
#define NITER16 (CMAX/16)   // 10 iterations, 16 candidates/wave/iter
#define FEAT (NHEAD*HEAD_DIM)

// ===== Geometry: LOCKED bit-exact numpy-fp32 emulation (R13 PASSED) =====
// M1 chain (noblas), M2 chain, M3 sgemm-FMA, einsum chain, cc chain; all
// under `#pragma clang fp contract(off)`, FMA only via __builtin_fmaf.
// R25: fused single kernel (R22/R23 infra-failed; R24 two-kernel passed,
// supporting the outage theory). Every thread runs the locked chain for
// its block's l -> candidate sets bit-identical, no broadcast barrier.

__device__ void np_inv3x3_f32(const float* M, float inv[3][3]) {
#pragma clang fp contract(off)
    float A[3][3]; int piv[3];
    for (int i=0;i<3;i++) { A[i][0]=M[i*3+0]; A[i][1]=M[i*3+1]; A[i][2]=M[i*3+2]; }
    for (int kk=0;kk<3;kk++) {
        int p = kk;
        float colmax = fabsf(A[kk][kk]);
        for (int i=kk+1;i<3;i++) { float vv=fabsf(A[i][kk]); if (vv>colmax){colmax=vv;p=i;} }
        piv[kk] = p;
        if (p!=kk) { for(int j=0;j<3;j++){float tmp=A[kk][j];A[kk][j]=A[p][j];A[p][j]=tmp;} }
        const float rp = 1.0f / A[kk][kk];
        for (int i=kk+1;i<3;i++) A[i][kk] = A[i][kk] * rp;
        for (int i=kk+1;i<3;i++)
            for (int j=kk+1;j<3;j++)
                A[i][j] = A[i][j] - A[i][kk]*A[kk][j];
    }
    for (int col=0; col<3; col++) {
        float b[3] = {0.f,0.f,0.f}; b[col] = 1.0f;
        for (int kk=0;kk<3;kk++) if (piv[kk]!=kk) { float tmp=b[kk]; b[kk]=b[piv[kk]]; b[piv[kk]]=tmp; }
        for (int i=1;i<3;i++)
            for (int kk=0;kk<i;kk++)
                b[i] = b[i] - A[i][kk]*b[kk];
        for (int kk=2;kk>=0;kk--) {
            b[kk] = b[kk] / A[kk][kk];
            for (int i=0;i<kk;i++)
                b[i] = b[i] - A[i][kk]*b[kk];
        }
        inv[0][col]=b[0]; inv[1][col]=b[1]; inv[2][col]=b[2];
    }
}

__device__ void mm3_chain(const float A[3][3], const float B[3][3], float C[3][3]) {
#pragma clang fp contract(off)
    for (int i=0;i<3;i++)
        for (int j=0;j<3;j++) {
            float acc = A[i][0]*B[0][j];
            acc = acc + A[i][1]*B[1][j];
            acc = acc + A[i][2]*B[2][j];
            C[i][j] = acc;
        }
}
__device__ void mm3_fma(const float A[3][3], const float B[3][3], float C[3][3]) {
#pragma clang fp contract(off)
    for (int i=0;i<3;i++)
        for (int j=0;j<3;j++) {
            float acc = A[i][0]*B[0][j];
            acc = __builtin_fmaf(A[i][1], B[1][j], acc);
            acc = __builtin_fmaf(A[i][2], B[2][j], acc);
            C[i][j] = acc;
        }
}
__device__ float einsum_row(const float Fi[3], float x, float y) {
#pragma clang fp contract(off)
    float acc = Fi[0]*x;
    acc = acc + Fi[1]*y;
    acc = acc + Fi[2]*1.0f;
    return acc;
}

// ===== R25: fused + 4-lanes-per-candidate gather loop =====
// vs R24 (89.8 us):
//  (1) geo kernel fused in (saves a serialized dispatch + launch gap +
//      ws round-trip). All threads compute the chain -> no extra barrier.
//  (2) lane layout 8->4 lanes/candidate: lane owns 8 dims (2x float4 of
//      Q/K/V). Dot needs only shfl_xor 1 and 2 -> both quad_perm DPP
//      (VALU pipe), ZERO ds ops in the hot loop (xor-4 was ds_swizzle).
//      10 iters, 10 exp/lane (was 20), same 40x16B gathers/lane.
//      Softmax formula unchanged from R24 -> absmax stays ~2e-3 scale.

__global__ __launch_bounds__(512) void one2many_fused(
    const float* __restrict__ q, const float* __restrict__ k, const float* __restrict__ v,
    const float* __restrict__ K0, const float* __restrict__ K1,
    const float* __restrict__ R, const float* __restrict__ t,
    float* __restrict__ out)
{
#pragma clang fp contract(off)
    __shared__ int s_cand[CMAX];
    __shared__ int s_cnt;

    const int bxi = blockIdx.x;
    const int l   = (bxi >> 3) + (bxi & 7) * 160;   // XCD-contiguous bijection on [0,1280)
    const int tid = threadIdx.x;

    if (tid == 0) s_cnt = 0;

    const int h    = tid >> 6;          // wave = head
    const int lane = tid & 63;
    const int grp  = lane >> 2;         // candidate sub-index within 16-group
    const int dj   = (lane & 3) << 3;   // dim offset 0,8,16,24

    // q: 8 floats per lane; issue early (independent of geometry/scan)
    const float4 qa = *(const float4*)(q + l*FEAT + h*HEAD_DIM + dj);
    const float4 qb = *(const float4*)(q + l*FEAT + h*HEAD_DIM + dj + 4);

    // ---- geometry: locked bit-exact chain, all threads (uniform) ----
    float slope, icpt; bool mode;
    {
        float i0[3][3], i1[3][3], A[3][3], B[3][3], T1[3][3], T2[3][3], Fm[3][3], Rm[3][3];
        np_inv3x3_f32(K0, i0);
        np_inv3x3_f32(K1, i1);
        for (int i=0;i<3;i++)
            for (int j=0;j<3;j++) { A[i][j] = i1[j][i]; Rm[i][j] = R[i*3+j]; }
        const float t0=t[0], t1=t[1], t2=t[2];
        B[0][0]=0.f;  B[0][1]=-t2;  B[0][2]=t1;
        B[1][0]=t2;   B[1][1]=0.f;  B[1][2]=-t0;
        B[2][0]=-t1;  B[2][1]=t0;   B[2][2]=0.f;
        mm3_chain(A,B,T1);      // noblas (swapaxes view)
        mm3_chain(T1,Rm,T2);    // T1 @ I
        mm3_fma(T2,i0,Fm);      // sgemm FMA
        const float xl = (float)(l % IMG_W);
        const float yl = (float)(l / IMG_W);
        const float la = einsum_row(Fm[0], xl, yl);
        const float lb = einsum_row(Fm[1], xl, yl);
        const float lc = einsum_row(Fm[2], xl, yl);
        mode = fabsf(lb) > fabsf(la);
        const float denom = mode ? lb : la;
        slope = (mode ? -la : -lb) / denom;
        icpt  = (-lc) / denom;
    }

    __syncthreads();   // s_cnt=0 visible

    // ---- candidate collection: identical fp32 band test ----
    for (int m = tid; m < NPIX; m += 512) {
        const float xm = (float)(m % IMG_W), ym = (float)(m / IMG_W);
        const float tin  = mode ? xm : ym;
        const float tchk = mode ? ym : xm;
        const float mu = slope * tin;
        const float cc = mu + icpt;
        const float hi = cc + 2.0f;
        const float lo = cc - 2.0f;
        if ((tchk < hi) && (tchk > lo) && m != 0) {
            int pos = atomicAdd(&s_cnt, 1);
            if (pos < CMAX) s_cand[pos] = m;
        }
    }
    __syncthreads();
    const int nc = min(s_cnt, CMAX);

    const float* kh = k + h*HEAD_DIM + dj;
    const float* vh = v + h*HEAD_DIM + dj;

    // ---- single-pass QK+softmax+AV; DPP-only cross-lane in loop ----
    float4 aA = make_float4(0.f,0.f,0.f,0.f);
    float4 aB = make_float4(0.f,0.f,0.f,0.f);
    float ps = 0.f;
    #pragma unroll
    for (int i = 0; i < NITER16; i++) {
        const int ci  = (i << 4) + grp;
        const int row = s_cand[(ci < nc) ? ci : 0];
        const size_t off = (size_t)row * FEAT;
        const float4 ka = *(const float4*)(kh + off);
        const float4 kb = *(const float4*)(kh + off + 4);
        const float4 va = *(const float4*)(vh + off);
        const float4 vb = *(const float4*)(vh + off + 4);
        float p = qa.x*ka.x;
        p = __builtin_fmaf(qa.y, ka.y, p);
        p = __builtin_fmaf(qa.z, ka.z, p);
        p = __builtin_fmaf(qa.w, ka.w, p);
        p = __builtin_fmaf(qb.x, kb.x, p);
        p = __builtin_fmaf(qb.y, kb.y, p);
        p = __builtin_fmaf(qb.z, kb.z, p);
        p = __builtin_fmaf(qb.w, kb.w, p);
        p += __shfl_xor(p, 1);              // quad_perm DPP
        p += __shfl_xor(p, 2);              // quad_perm DPP -> full dot in all 4 lanes
        const float e = (ci < nc) ? __expf(p * 0.17677669529663687f) : 0.0f;
        ps += e;
        aA.x = __builtin_fmaf(e, va.x, aA.x);
        aA.y = __builtin_fmaf(e, va.y, aA.y);
        aA.z = __builtin_fmaf(e, va.z, aA.z);
        aA.w = __builtin_fmaf(e, va.w, aA.w);
        aB.x = __builtin_fmaf(e, vb.x, aB.x);
        aB.y = __builtin_fmaf(e, vb.y, aB.y);
        aB.z = __builtin_fmaf(e, vb.z, aB.z);
        aB.w = __builtin_fmaf(e, vb.w, aB.w);
    }

    // ---- reduce over the 16 candidate groups (bits 2..5 of lane) ----
    #pragma unroll
    for (int o = 4; o <= 32; o <<= 1) {
        aA.x += __shfl_xor(aA.x, o);
        aA.y += __shfl_xor(aA.y, o);
        aA.z += __shfl_xor(aA.z, o);
        aA.w += __shfl_xor(aA.w, o);
        aB.x += __shfl_xor(aB.x, o);
        aB.y += __shfl_xor(aB.y, o);
        aB.z += __shfl_xor(aB.z, o);
        aB.w += __shfl_xor(aB.w, o);
        ps   += __shfl_xor(ps, o);
    }

    if (lane < 4) {
        float4 rA, rB;
        if (nc > 0) {
            rA.x = aA.x/ps; rA.y = aA.y/ps; rA.z = aA.z/ps; rA.w = aA.w/ps;
            rB.x = aB.x/ps; rB.y = aB.y/ps; rB.z = aB.z/ps; rB.w = aB.w/ps;
        } else {
            rA.x = rA.y = rA.z = rA.w = 0.0f;
            rB.x = rB.y = rB.z = rB.w = 0.0f;
        }
        *(float4*)(out + l*FEAT + h*HEAD_DIM + dj)     = rA;
        *(float4*)(out + l*FEAT + h*HEAD_DIM + dj + 4) = rB;
    }
}

extern "C" void kernel_launch(void* const* d_in, const int* in_sizes, int n_in,
                              void* d_out, int out_size, void* d_ws, size_t ws_size,
                              hipStream_t stream) {
    const float* q  = (const float*)d_in[0];
    const float* k  = (const float*)d_in[1];
    const float* v  = (const float*)d_in[2];
    const float* K0 = (const float*)d_in[3];
    const float* K1 = (const float*)d_in[4];
    const float* R  = (const float*)d_in[5];
    const float* t  = (const float*)d_in[6];
    float* out = (float*)d_out;
    (void)d_ws; (void)ws_size;
    one2many_fused<<<NPIX, 512, 0, stream>>>(q, k, v, K0, K1, R, t, out);
}

// Round 5
// 100.149 us; speedup vs baseline: 1.1852x; 1.1852x over previous
//
#include <hip/hip_runtime.h>
#include <math.h>

#define NHEAD 8
#define HEAD_DIM 32
#define IMG_H 32
#define IMG_W 40
#define NPIX (IMG_H*IMG_W)
#define CMAX 160
#define NITER16 (CMAX/16)   // 10 iterations, 16 candidates/wave/iter
#define FEAT (NHEAD*HEAD_DIM)

// ===== Geometry: LOCKED bit-exact numpy-fp32 emulation (R13 PASSED) =====
// M1 chain (noblas), M2 chain, M3 sgemm-FMA, einsum chain, cc chain; all
// under `#pragma clang fp contract(off)`, FMA only via __builtin_fmaf.
// R26: geometry PERMANENTLY stays a separate microkernel. R25 fused it
// into all threads -> LU's runtime-pivot arrays demoted to scratch/LDS
// (VGPR=40, LDS=13312, attn 40->61 us). One 1280-thread dispatch is ~4 us.

__device__ void np_inv3x3_f32(const float* M, float inv[3][3]) {
#pragma clang fp contract(off)
    float A[3][3]; int piv[3];
    for (int i=0;i<3;i++) { A[i][0]=M[i*3+0]; A[i][1]=M[i*3+1]; A[i][2]=M[i*3+2]; }
    for (int kk=0;kk<3;kk++) {
        int p = kk;
        float colmax = fabsf(A[kk][kk]);
        for (int i=kk+1;i<3;i++) { float vv=fabsf(A[i][kk]); if (vv>colmax){colmax=vv;p=i;} }
        piv[kk] = p;
        if (p!=kk) { for(int j=0;j<3;j++){float tmp=A[kk][j];A[kk][j]=A[p][j];A[p][j]=tmp;} }
        const float rp = 1.0f / A[kk][kk];
        for (int i=kk+1;i<3;i++) A[i][kk] = A[i][kk] * rp;
        for (int i=kk+1;i<3;i++)
            for (int j=kk+1;j<3;j++)
                A[i][j] = A[i][j] - A[i][kk]*A[kk][j];
    }
    for (int col=0; col<3; col++) {
        float b[3] = {0.f,0.f,0.f}; b[col] = 1.0f;
        for (int kk=0;kk<3;kk++) if (piv[kk]!=kk) { float tmp=b[kk]; b[kk]=b[piv[kk]]; b[piv[kk]]=tmp; }
        for (int i=1;i<3;i++)
            for (int kk=0;kk<i;kk++)
                b[i] = b[i] - A[i][kk]*b[kk];
        for (int kk=2;kk>=0;kk--) {
            b[kk] = b[kk] / A[kk][kk];
            for (int i=0;i<kk;i++)
                b[i] = b[i] - A[i][kk]*b[kk];
        }
        inv[0][col]=b[0]; inv[1][col]=b[1]; inv[2][col]=b[2];
    }
}

__device__ void mm3_chain(const float A[3][3], const float B[3][3], float C[3][3]) {
#pragma clang fp contract(off)
    for (int i=0;i<3;i++)
        for (int j=0;j<3;j++) {
            float acc = A[i][0]*B[0][j];
            acc = acc + A[i][1]*B[1][j];
            acc = acc + A[i][2]*B[2][j];
            C[i][j] = acc;
        }
}
__device__ void mm3_fma(const float A[3][3], const float B[3][3], float C[3][3]) {
#pragma clang fp contract(off)
    for (int i=0;i<3;i++)
        for (int j=0;j<3;j++) {
            float acc = A[i][0]*B[0][j];
            acc = __builtin_fmaf(A[i][1], B[1][j], acc);
            acc = __builtin_fmaf(A[i][2], B[2][j], acc);
            C[i][j] = acc;
        }
}
__device__ float einsum_row(const float Fi[3], float x, float y) {
#pragma clang fp contract(off)
    float acc = Fi[0]*x;
    acc = acc + Fi[1]*y;
    acc = acc + Fi[2]*1.0f;
    return acc;
}

__global__ __launch_bounds__(64) void geo_kernel(
    const float* __restrict__ K0, const float* __restrict__ K1,
    const float* __restrict__ R, const float* __restrict__ t,
    float4* __restrict__ geo)
{
#pragma clang fp contract(off)
    const int l = blockIdx.x * 64 + threadIdx.x;   // 20*64 = 1280 exactly
    float i0[3][3], i1[3][3], A[3][3], B[3][3], T1[3][3], T2[3][3], F[3][3], Rm[3][3];
    np_inv3x3_f32(K0, i0);
    np_inv3x3_f32(K1, i1);
    for (int i=0;i<3;i++)
        for (int j=0;j<3;j++) { A[i][j] = i1[j][i]; Rm[i][j] = R[i*3+j]; }
    const float t0=t[0], t1=t[1], t2=t[2];
    B[0][0]=0.f;  B[0][1]=-t2;  B[0][2]=t1;
    B[1][0]=t2;   B[1][1]=0.f;  B[1][2]=-t0;
    B[2][0]=-t1;  B[2][1]=t0;   B[2][2]=0.f;
    mm3_chain(A,B,T1);      // noblas (swapaxes view)
    mm3_chain(T1,Rm,T2);    // T1 @ I
    mm3_fma(T2,i0,F);       // sgemm FMA

    const float xl = (float)(l % IMG_W);
    const float yl = (float)(l / IMG_W);
    const float la = einsum_row(F[0], xl, yl);
    const float lb = einsum_row(F[1], xl, yl);
    const float lc = einsum_row(F[2], xl, yl);
    const bool  mode  = fabsf(lb) > fabsf(la);
    const float denom = mode ? lb : la;
    const float slope = (mode ? -la : -lb) / denom;
    const float icpt  = (-lc) / denom;
    geo[l] = make_float4(slope, icpt, mode ? 1.0f : 0.0f, 0.0f);
}

// ===== R26: R24 structure (89.8 us) + 4-lanes-per-candidate loop =====
// R24's single-pass softmax kept (sum(e*v)/sum(e), no max subtract).
// Lane layout 8->4 lanes/candidate: lane owns 8 dims (2x float4 of
// Q/K/V). Dot needs only shfl_xor 1 and 2 -> both quad_perm DPP (VALU
// pipe), ZERO ds ops in the hot loop (xor-4 was ds_swizzle). 10 iters,
// 10 exp/lane (was 20), same 40x16B gathers/lane. R25 confirmed this
// summation tree's absmax (~1e-3) independently of the failed fusion.

__global__ __launch_bounds__(512) void one2many_attn(
    const float* __restrict__ q, const float* __restrict__ k, const float* __restrict__ v,
    const float4* __restrict__ geo, float* __restrict__ out)
{
#pragma clang fp contract(off)
    __shared__ int s_cand[CMAX];
    __shared__ int s_cnt;

    const int bx  = blockIdx.x;
    const int l   = (bx >> 3) + (bx & 7) * 160;   // XCD-contiguous bijection on [0,1280)
    const int tid = threadIdx.x;

    if (tid == 0) s_cnt = 0;

    const float4 g = geo[l];            // broadcast load (L2-resident)
    const float slope = g.x;
    const float icpt  = g.y;
    const bool  mode  = (g.z != 0.0f);

    const int h    = tid >> 6;          // wave = head
    const int lane = tid & 63;
    const int grp  = lane >> 2;         // candidate sub-index within 16-group
    const int dj   = (lane & 3) << 3;   // dim offset 0,8,16,24

    // q: 8 floats per lane; issue early (independent of scan)
    const float4 qa = *(const float4*)(q + l*FEAT + h*HEAD_DIM + dj);
    const float4 qb = *(const float4*)(q + l*FEAT + h*HEAD_DIM + dj + 4);

    __syncthreads();   // s_cnt=0 visible

    // ---- candidate collection: identical fp32 band test ----
    for (int m = tid; m < NPIX; m += 512) {
        const float xm = (float)(m % IMG_W), ym = (float)(m / IMG_W);
        const float tin  = mode ? xm : ym;
        const float tchk = mode ? ym : xm;
        const float mu = slope * tin;
        const float cc = mu + icpt;
        const float hi = cc + 2.0f;
        const float lo = cc - 2.0f;
        if ((tchk < hi) && (tchk > lo) && m != 0) {
            int pos = atomicAdd(&s_cnt, 1);
            if (pos < CMAX) s_cand[pos] = m;
        }
    }
    __syncthreads();
    const int nc = min(s_cnt, CMAX);

    const float* kh = k + h*HEAD_DIM + dj;
    const float* vh = v + h*HEAD_DIM + dj;

    // ---- single-pass QK+softmax+AV; DPP-only cross-lane in loop ----
    float4 aA = make_float4(0.f,0.f,0.f,0.f);
    float4 aB = make_float4(0.f,0.f,0.f,0.f);
    float ps = 0.f;
    #pragma unroll
    for (int i = 0; i < NITER16; i++) {
        const int ci  = (i << 4) + grp;
        const int row = s_cand[(ci < nc) ? ci : 0];
        const size_t off = (size_t)row * FEAT;
        const float4 ka = *(const float4*)(kh + off);
        const float4 kb = *(const float4*)(kh + off + 4);
        const float4 va = *(const float4*)(vh + off);
        const float4 vb = *(const float4*)(vh + off + 4);
        float p = qa.x*ka.x;
        p = __builtin_fmaf(qa.y, ka.y, p);
        p = __builtin_fmaf(qa.z, ka.z, p);
        p = __builtin_fmaf(qa.w, ka.w, p);
        p = __builtin_fmaf(qb.x, kb.x, p);
        p = __builtin_fmaf(qb.y, kb.y, p);
        p = __builtin_fmaf(qb.z, kb.z, p);
        p = __builtin_fmaf(qb.w, kb.w, p);
        p += __shfl_xor(p, 1);              // quad_perm DPP
        p += __shfl_xor(p, 2);              // quad_perm DPP -> full dot in all 4 lanes
        const float e = (ci < nc) ? __expf(p * 0.17677669529663687f) : 0.0f;
        ps += e;
        aA.x = __builtin_fmaf(e, va.x, aA.x);
        aA.y = __builtin_fmaf(e, va.y, aA.y);
        aA.z = __builtin_fmaf(e, va.z, aA.z);
        aA.w = __builtin_fmaf(e, va.w, aA.w);
        aB.x = __builtin_fmaf(e, vb.x, aB.x);
        aB.y = __builtin_fmaf(e, vb.y, aB.y);
        aB.z = __builtin_fmaf(e, vb.z, aB.z);
        aB.w = __builtin_fmaf(e, vb.w, aB.w);
    }

    // ---- reduce over the 16 candidate groups (bits 2..5 of lane) ----
    #pragma unroll
    for (int o = 4; o <= 32; o <<= 1) {
        aA.x += __shfl_xor(aA.x, o);
        aA.y += __shfl_xor(aA.y, o);
        aA.z += __shfl_xor(aA.z, o);
        aA.w += __shfl_xor(aA.w, o);
        aB.x += __shfl_xor(aB.x, o);
        aB.y += __shfl_xor(aB.y, o);
        aB.z += __shfl_xor(aB.z, o);
        aB.w += __shfl_xor(aB.w, o);
        ps   += __shfl_xor(ps, o);
    }

    if (lane < 4) {
        float4 rA, rB;
        if (nc > 0) {
            rA.x = aA.x/ps; rA.y = aA.y/ps; rA.z = aA.z/ps; rA.w = aA.w/ps;
            rB.x = aB.x/ps; rB.y = aB.y/ps; rB.z = aB.z/ps; rB.w = aB.w/ps;
        } else {
            rA.x = rA.y = rA.z = rA.w = 0.0f;
            rB.x = rB.y = rB.z = rB.w = 0.0f;
        }
        *(float4*)(out + l*FEAT + h*HEAD_DIM + dj)     = rA;
        *(float4*)(out + l*FEAT + h*HEAD_DIM + dj + 4) = rB;
    }
}

extern "C" void kernel_launch(void* const* d_in, const int* in_sizes, int n_in,
                              void* d_out, int out_size, void* d_ws, size_t ws_size,
                              hipStream_t stream) {
    const float* q  = (const float*)d_in[0];
    const float* k  = (const float*)d_in[1];
    const float* v  = (const float*)d_in[2];
    const float* K0 = (const float*)d_in[3];
    const float* K1 = (const float*)d_in[4];
    const float* R  = (const float*)d_in[5];
    const float* t  = (const float*)d_in[6];
    float* out = (float*)d_out;
    float4* geo = (float4*)d_ws;        // 1280 x 16 B = 20 KB
    geo_kernel<<<NPIX/64, 64, 0, stream>>>(K0, K1, R, t, geo);
    one2many_attn<<<NPIX, 512, 0, stream>>>(q, k, v, geo, out);
}

// Round 6
// 87.910 us; speedup vs baseline: 1.3502x; 1.1392x over previous
//
#include <hip/hip_runtime.h>
#include <math.h>

#define NHEAD 8
#define HEAD_DIM 32
#define IMG_H 32
#define IMG_W 40
#define NPIX (IMG_H*IMG_W)
#define CMAX 160
#define NITER (CMAX/8)   // 20
#define FEAT (NHEAD*HEAD_DIM)

// ===== Geometry: LOCKED bit-exact numpy-fp32 emulation =====
// R27: np LU inversion rewritten with EXPLICIT SCALARS + pivot selects —
// arithmetic sequence is 1:1 with the locked array version (strict-'>'
// pivot search, reciprocal-mul elimination, '/' back-substitution), only
// data movement (row swaps / b-permutation) became cndmask selects. This
// removes every runtime-indexed array -> register-resident -> safe to fuse
// into the attention kernel (R25's scratch/LDS-spill disaster is avoided:
// that kernel showed VGPR=40/LDS=13312 from indexed-pivot scratch demotion).

__device__ __forceinline__ void np_inv3x3_reg(const float* __restrict__ M, float inv[3][3]) {
#pragma clang fp contract(off)
    float a00=M[0], a01=M[1], a02=M[2];
    float a10=M[3], a11=M[4], a12=M[5];
    float a20=M[6], a21=M[7], a22=M[8];

    // ---- kk=0: pivot search (strictly-greater update, as numpy) ----
    const float c0 = fabsf(a00), c1 = fabsf(a10), c2 = fabsf(a20);
    const bool s1 = c1 > c0;
    const float cm = s1 ? c1 : c0;
    const bool s2 = c2 > cm;
    const bool q1 = s1 && !s2;      // pivot row 1
    const bool q2 = s2;             // pivot row 2 (q1,q2 mutually exclusive)
    {   // full row swap 0 <-> p0
        const float n0 = q2 ? a20 : (q1 ? a10 : a00);
        const float n1 = q2 ? a21 : (q1 ? a11 : a01);
        const float n2 = q2 ? a22 : (q1 ? a12 : a02);
        const float m0 = q1 ? a00 : a10, m1 = q1 ? a01 : a11, m2 = q1 ? a02 : a12;
        const float r0 = q2 ? a00 : a20, r1 = q2 ? a01 : a21, r2 = q2 ? a02 : a22;
        a00=n0; a01=n1; a02=n2;
        a10=m0; a11=m1; a12=m2;
        a20=r0; a21=r1; a22=r2;
    }
    const float rp0 = 1.0f / a00;
    a10 = a10 * rp0;
    a20 = a20 * rp0;
    a11 = a11 - a10*a01;
    a12 = a12 - a10*a02;
    a21 = a21 - a20*a01;
    a22 = a22 - a20*a02;

    // ---- kk=1: pivot search over rows 1,2 ----
    const bool sB = fabsf(a21) > fabsf(a11);
    {   // full row swap 1 <-> 2 (includes factored column 0, as numpy)
        const float t0 = sB ? a20 : a10, t1 = sB ? a21 : a11, t2 = sB ? a22 : a12;
        const float u0 = sB ? a10 : a20, u1 = sB ? a11 : a21, u2 = sB ? a12 : a22;
        a10=t0; a11=t1; a12=t2;
        a20=u0; a21=u1; a22=u2;
    }
    const float rp1 = 1.0f / a11;
    a21 = a21 * rp1;
    a22 = a22 - a21*a12;
    // kk=2: pivot is row 2, no swap, no elimination.

    // ---- solve A x = e_col for col=0,1,2 (constant-trip, unrolled) ----
    #pragma unroll
    for (int col = 0; col < 3; col++) {
        float b0 = (col==0) ? 1.0f : 0.0f;
        float b1 = (col==1) ? 1.0f : 0.0f;
        float b2 = (col==2) ? 1.0f : 0.0f;
        {   // apply piv[0]
            const float w0 = q2 ? b2 : (q1 ? b1 : b0);
            const float w1 = q1 ? b0 : b1;
            const float w2 = q2 ? b0 : b2;
            b0=w0; b1=w1; b2=w2;
        }
        {   // apply piv[1]
            const float x1 = sB ? b2 : b1;
            const float x2 = sB ? b1 : b2;
            b1=x1; b2=x2;
        }
        // forward substitution (i=1:kk=0; i=2:kk=0,1)
        b1 = b1 - a10*b0;
        b2 = b2 - a20*b0;
        b2 = b2 - a21*b1;
        // back substitution (kk=2: i=0,1; kk=1: i=0; kk=0)
        b2 = b2 / a22;
        b0 = b0 - a02*b2;
        b1 = b1 - a12*b2;
        b1 = b1 / a11;
        b0 = b0 - a01*b1;
        b0 = b0 / a00;
        inv[0][col]=b0; inv[1][col]=b1; inv[2][col]=b2;
    }
}

__device__ __forceinline__ void mm3_chain(const float A[3][3], const float B[3][3], float C[3][3]) {
#pragma clang fp contract(off)
    for (int i=0;i<3;i++)
        for (int j=0;j<3;j++) {
            float acc = A[i][0]*B[0][j];
            acc = acc + A[i][1]*B[1][j];
            acc = acc + A[i][2]*B[2][j];
            C[i][j] = acc;
        }
}
__device__ __forceinline__ void mm3_fma(const float A[3][3], const float B[3][3], float C[3][3]) {
#pragma clang fp contract(off)
    for (int i=0;i<3;i++)
        for (int j=0;j<3;j++) {
            float acc = A[i][0]*B[0][j];
            acc = __builtin_fmaf(A[i][1], B[1][j], acc);
            acc = __builtin_fmaf(A[i][2], B[2][j], acc);
            C[i][j] = acc;
        }
}
__device__ __forceinline__ float einsum_row(const float Fi[3], float x, float y) {
#pragma clang fp contract(off)
    float acc = Fi[0]*x;
    acc = acc + Fi[1]*y;
    acc = acc + Fi[2]*1.0f;
    return acc;
}

// ===== R27: fused single kernel = R24 8-lane attn + register-LU geometry =====
// R26 lesson: 4-lane layout regressed (89.8->100.1) — its two half-row loads
// each touch BOTH 64-B sectors of every candidate row (2x sector requests on
// a request-limited gather). 8-lane layout: one load = one contiguous 128-B
// row slice. R24's single-pass softmax kept (sum(e*v)/sum(e), no max
// subtract; scores ~N(0,1) so exp overflow-impossible).

__global__ __launch_bounds__(512) void one2many_fused(
    const float* __restrict__ q, const float* __restrict__ k, const float* __restrict__ v,
    const float* __restrict__ K0, const float* __restrict__ K1,
    const float* __restrict__ R, const float* __restrict__ t,
    float* __restrict__ out)
{
#pragma clang fp contract(off)
    __shared__ int s_cand[CMAX];
    __shared__ int s_cnt;

    const int bx  = blockIdx.x;
    const int l   = (bx >> 3) + (bx & 7) * 160;   // XCD-contiguous bijection on [0,1280)
    const int tid = threadIdx.x;

    if (tid == 0) s_cnt = 0;

    const int h    = tid >> 6;          // wave = head
    const int lane = tid & 63;
    const int grp  = lane >> 3;         // candidate sub-index within 8-group
    const int dj   = (lane & 7) << 2;   // dim offset 0,4,...,28

    // broadcast q load: independent of geometry/scan -> issue early
    const float4 q4 = *(const float4*)(q + l*FEAT + h*HEAD_DIM + dj);

    // ---- geometry: locked bit-exact chain, all threads, register-resident ----
    float slope, icpt; bool mode;
    {
        float i0[3][3], i1[3][3], A[3][3], B[3][3], T1[3][3], T2[3][3], Fm[3][3], Rm[3][3];
        np_inv3x3_reg(K0, i0);
        np_inv3x3_reg(K1, i1);
        for (int i=0;i<3;i++)
            for (int j=0;j<3;j++) { A[i][j] = i1[j][i]; Rm[i][j] = R[i*3+j]; }
        const float t0=t[0], t1=t[1], t2=t[2];
        B[0][0]=0.f;  B[0][1]=-t2;  B[0][2]=t1;
        B[1][0]=t2;   B[1][1]=0.f;  B[1][2]=-t0;
        B[2][0]=-t1;  B[2][1]=t0;   B[2][2]=0.f;
        mm3_chain(A,B,T1);      // noblas (swapaxes view)
        mm3_chain(T1,Rm,T2);    // T1 @ I
        mm3_fma(T2,i0,Fm);      // sgemm FMA
        const float xl = (float)(l % IMG_W);
        const float yl = (float)(l / IMG_W);
        const float la = einsum_row(Fm[0], xl, yl);
        const float lb = einsum_row(Fm[1], xl, yl);
        const float lc = einsum_row(Fm[2], xl, yl);
        mode = fabsf(lb) > fabsf(la);
        const float denom = mode ? lb : la;
        slope = (mode ? -la : -lb) / denom;
        icpt  = (-lc) / denom;
    }

    __syncthreads();   // s_cnt=0 visible

    // ---- candidate collection: identical fp32 band test ----
    for (int m = tid; m < NPIX; m += 512) {
        const float xm = (float)(m % IMG_W), ym = (float)(m / IMG_W);
        const float tin  = mode ? xm : ym;
        const float tchk = mode ? ym : xm;
        const float mu = slope * tin;
        const float cc = mu + icpt;
        const float hi = cc + 2.0f;
        const float lo = cc - 2.0f;
        if ((tchk < hi) && (tchk > lo) && m != 0) {
            int pos = atomicAdd(&s_cnt, 1);
            if (pos < CMAX) s_cand[pos] = m;
        }
    }
    __syncthreads();
    const int nc = min(s_cnt, CMAX);

    const float* kh = k + h*HEAD_DIM + dj;
    const float* vh = v + h*HEAD_DIM + dj;

    // ---- single-pass QK+softmax+AV (no max subtraction; exp-safe) ----
    float ax = 0.f, ay = 0.f, az = 0.f, aw = 0.f, ps = 0.f;
    #pragma unroll
    for (int i = 0; i < NITER; i++) {
        const int ci  = (i << 3) + grp;
        const int row = s_cand[(ci < nc) ? ci : 0];
        const size_t off = (size_t)row * FEAT;
        const float4 kk = *(const float4*)(kh + off);
        const float4 vv = *(const float4*)(vh + off);
        float p = q4.x*kk.x;
        p = __builtin_fmaf(q4.y, kk.y, p);
        p = __builtin_fmaf(q4.z, kk.z, p);
        p = __builtin_fmaf(q4.w, kk.w, p);
        p += __shfl_xor(p, 1);
        p += __shfl_xor(p, 2);
        p += __shfl_xor(p, 4);              // full dot, identical across 8-group
        const float e = (ci < nc) ? __expf(p * 0.17677669529663687f) : 0.0f;
        ps += e;
        ax = __builtin_fmaf(e, vv.x, ax);
        ay = __builtin_fmaf(e, vv.y, ay);
        az = __builtin_fmaf(e, vv.z, az);
        aw = __builtin_fmaf(e, vv.w, aw);
    }

    // ---- reduce over the 8 candidate groups (bits 3..5 of lane) ----
    #pragma unroll
    for (int o = 8; o <= 32; o <<= 1) {
        ax += __shfl_xor(ax, o);
        ay += __shfl_xor(ay, o);
        az += __shfl_xor(az, o);
        aw += __shfl_xor(aw, o);
        ps += __shfl_xor(ps, o);
    }

    if (lane < 8) {
        float4 r;
        if (nc > 0) { r.x = ax/ps; r.y = ay/ps; r.z = az/ps; r.w = aw/ps; }
        else        { r.x = r.y = r.z = r.w = 0.0f; }
        *(float4*)(out + l*FEAT + h*HEAD_DIM + dj) = r;
    }
}

extern "C" void kernel_launch(void* const* d_in, const int* in_sizes, int n_in,
                              void* d_out, int out_size, void* d_ws, size_t ws_size,
                              hipStream_t stream) {
    const float* q  = (const float*)d_in[0];
    const float* k  = (const float*)d_in[1];
    const float* v  = (const float*)d_in[2];
    const float* K0 = (const float*)d_in[3];
    const float* K1 = (const float*)d_in[4];
    const float* R  = (const float*)d_in[5];
    const float* t  = (const float*)d_in[6];
    float* out = (float*)d_out;
    (void)d_ws; (void)ws_size;
    one2many_fused<<<NPIX, 512, 0, stream>>>(q, k, v, K0, K1, R, t, out);
}

// Round 7
// 86.188 us; speedup vs baseline: 1.3772x; 1.0200x over previous
//
#include <hip/hip_runtime.h>
#include <math.h>

#define NHEAD 8
#define HEAD_DIM 32
#define IMG_H 32
#define IMG_W 40
#define NPIX (IMG_H*IMG_W)
#define CMAX 160
#define NITER (CMAX/8)   // 20
#define FEAT (NHEAD*HEAD_DIM)

// ===== Geometry: LOCKED bit-exact numpy-fp32 emulation =====
// R27: register-LU (explicit scalars + pivot selects, arithmetic 1:1 with
// numpy chain) -> fusable without scratch demotion. PASSED, absmax 2^-10.

__device__ __forceinline__ void np_inv3x3_reg(const float* __restrict__ M, float inv[3][3]) {
#pragma clang fp contract(off)
    float a00=M[0], a01=M[1], a02=M[2];
    float a10=M[3], a11=M[4], a12=M[5];
    float a20=M[6], a21=M[7], a22=M[8];

    // ---- kk=0: pivot search (strictly-greater update, as numpy) ----
    const float c0 = fabsf(a00), c1 = fabsf(a10), c2 = fabsf(a20);
    const bool s1 = c1 > c0;
    const float cm = s1 ? c1 : c0;
    const bool s2 = c2 > cm;
    const bool q1 = s1 && !s2;      // pivot row 1
    const bool q2 = s2;             // pivot row 2 (q1,q2 mutually exclusive)
    {   // full row swap 0 <-> p0
        const float n0 = q2 ? a20 : (q1 ? a10 : a00);
        const float n1 = q2 ? a21 : (q1 ? a11 : a01);
        const float n2 = q2 ? a22 : (q1 ? a12 : a02);
        const float m0 = q1 ? a00 : a10, m1 = q1 ? a01 : a11, m2 = q1 ? a02 : a12;
        const float r0 = q2 ? a00 : a20, r1 = q2 ? a01 : a21, r2 = q2 ? a02 : a22;
        a00=n0; a01=n1; a02=n2;
        a10=m0; a11=m1; a12=m2;
        a20=r0; a21=r1; a22=r2;
    }
    const float rp0 = 1.0f / a00;
    a10 = a10 * rp0;
    a20 = a20 * rp0;
    a11 = a11 - a10*a01;
    a12 = a12 - a10*a02;
    a21 = a21 - a20*a01;
    a22 = a22 - a20*a02;

    // ---- kk=1: pivot search over rows 1,2 ----
    const bool sB = fabsf(a21) > fabsf(a11);
    {   // full row swap 1 <-> 2 (includes factored column 0, as numpy)
        const float t0 = sB ? a20 : a10, t1 = sB ? a21 : a11, t2 = sB ? a22 : a12;
        const float u0 = sB ? a10 : a20, u1 = sB ? a11 : a21, u2 = sB ? a12 : a22;
        a10=t0; a11=t1; a12=t2;
        a20=u0; a21=u1; a22=u2;
    }
    const float rp1 = 1.0f / a11;
    a21 = a21 * rp1;
    a22 = a22 - a21*a12;
    // kk=2: pivot is row 2, no swap, no elimination.

    // ---- solve A x = e_col for col=0,1,2 (constant-trip, unrolled) ----
    #pragma unroll
    for (int col = 0; col < 3; col++) {
        float b0 = (col==0) ? 1.0f : 0.0f;
        float b1 = (col==1) ? 1.0f : 0.0f;
        float b2 = (col==2) ? 1.0f : 0.0f;
        {   // apply piv[0]
            const float w0 = q2 ? b2 : (q1 ? b1 : b0);
            const float w1 = q1 ? b0 : b1;
            const float w2 = q2 ? b0 : b2;
            b0=w0; b1=w1; b2=w2;
        }
        {   // apply piv[1]
            const float x1 = sB ? b2 : b1;
            const float x2 = sB ? b1 : b2;
            b1=x1; b2=x2;
        }
        // forward substitution (i=1:kk=0; i=2:kk=0,1)
        b1 = b1 - a10*b0;
        b2 = b2 - a20*b0;
        b2 = b2 - a21*b1;
        // back substitution (kk=2: i=0,1; kk=1: i=0; kk=0)
        b2 = b2 / a22;
        b0 = b0 - a02*b2;
        b1 = b1 - a12*b2;
        b1 = b1 / a11;
        b0 = b0 - a01*b1;
        b0 = b0 / a00;
        inv[0][col]=b0; inv[1][col]=b1; inv[2][col]=b2;
    }
}

__device__ __forceinline__ void mm3_chain(const float A[3][3], const float B[3][3], float C[3][3]) {
#pragma clang fp contract(off)
    for (int i=0;i<3;i++)
        for (int j=0;j<3;j++) {
            float acc = A[i][0]*B[0][j];
            acc = acc + A[i][1]*B[1][j];
            acc = acc + A[i][2]*B[2][j];
            C[i][j] = acc;
        }
}
__device__ __forceinline__ void mm3_fma(const float A[3][3], const float B[3][3], float C[3][3]) {
#pragma clang fp contract(off)
    for (int i=0;i<3;i++)
        for (int j=0;j<3;j++) {
            float acc = A[i][0]*B[0][j];
            acc = __builtin_fmaf(A[i][1], B[1][j], acc);
            acc = __builtin_fmaf(A[i][2], B[2][j], acc);
            C[i][j] = acc;
        }
}
__device__ __forceinline__ float einsum_row(const float Fi[3], float x, float y) {
#pragma clang fp contract(off)
    float acc = Fi[0]*x;
    acc = acc + Fi[1]*y;
    acc = acc + Fi[2]*1.0f;
    return acc;
}

// ===== R28: 256-thread blocks, wave owns TWO heads (h = w, w+4) =====
// vs R27 (87.9 us, fused, 512-thread blocks): with 512 threads a CU holds
// only 4 blocks (2048-thread cap) but grid/CU = 5 -> serialized 2nd round
// + tail; measured occupancy stuck ~39%. At 256 threads the WHOLE grid is
// co-resident (1280 threads/CU), and each wave issues 4 independent 16-B
// gathers/iter (K/V x 2 heads) -> 2x MLP for the L2-latency-bound loop.
// Per-(l,h) arithmetic order identical to R27 -> bit-identical output.

__global__ __launch_bounds__(256) void one2many_fused(
    const float* __restrict__ q, const float* __restrict__ k, const float* __restrict__ v,
    const float* __restrict__ K0, const float* __restrict__ K1,
    const float* __restrict__ R, const float* __restrict__ t,
    float* __restrict__ out)
{
#pragma clang fp contract(off)
    __shared__ int s_cand[CMAX];
    __shared__ int s_cnt;

    const int bx  = blockIdx.x;
    const int l   = (bx >> 3) + (bx & 7) * 160;   // XCD-contiguous bijection on [0,1280)
    const int tid = threadIdx.x;

    if (tid == 0) s_cnt = 0;

    const int w    = tid >> 6;          // wave index 0..3
    const int h0   = w;                 // first head
    const int h1   = w + 4;             // second head
    const int lane = tid & 63;
    const int grp  = lane >> 3;         // candidate sub-index within 8-group
    const int dj   = (lane & 7) << 2;   // dim offset 0,4,...,28

    // broadcast q loads: independent of geometry/scan -> issue early
    const float4 q4a = *(const float4*)(q + l*FEAT + h0*HEAD_DIM + dj);
    const float4 q4b = *(const float4*)(q + l*FEAT + h1*HEAD_DIM + dj);

    // ---- geometry: locked bit-exact chain, all threads, register-resident ----
    float slope, icpt; bool mode;
    {
        float i0[3][3], i1[3][3], A[3][3], B[3][3], T1[3][3], T2[3][3], Fm[3][3], Rm[3][3];
        np_inv3x3_reg(K0, i0);
        np_inv3x3_reg(K1, i1);
        for (int i=0;i<3;i++)
            for (int j=0;j<3;j++) { A[i][j] = i1[j][i]; Rm[i][j] = R[i*3+j]; }
        const float t0=t[0], t1=t[1], t2=t[2];
        B[0][0]=0.f;  B[0][1]=-t2;  B[0][2]=t1;
        B[1][0]=t2;   B[1][1]=0.f;  B[1][2]=-t0;
        B[2][0]=-t1;  B[2][1]=t0;   B[2][2]=0.f;
        mm3_chain(A,B,T1);      // noblas (swapaxes view)
        mm3_chain(T1,Rm,T2);    // T1 @ I
        mm3_fma(T2,i0,Fm);      // sgemm FMA
        const float xl = (float)(l % IMG_W);
        const float yl = (float)(l / IMG_W);
        const float la = einsum_row(Fm[0], xl, yl);
        const float lb = einsum_row(Fm[1], xl, yl);
        const float lc = einsum_row(Fm[2], xl, yl);
        mode = fabsf(lb) > fabsf(la);
        const float denom = mode ? lb : la;
        slope = (mode ? -la : -lb) / denom;
        icpt  = (-lc) / denom;
    }

    __syncthreads();   // s_cnt=0 visible

    // ---- candidate collection: identical fp32 band test ----
    for (int m = tid; m < NPIX; m += 256) {
        const float xm = (float)(m % IMG_W), ym = (float)(m / IMG_W);
        const float tin  = mode ? xm : ym;
        const float tchk = mode ? ym : xm;
        const float mu = slope * tin;
        const float cc = mu + icpt;
        const float hi = cc + 2.0f;
        const float lo = cc - 2.0f;
        if ((tchk < hi) && (tchk > lo) && m != 0) {
            int pos = atomicAdd(&s_cnt, 1);
            if (pos < CMAX) s_cand[pos] = m;
        }
    }
    __syncthreads();
    const int nc = min(s_cnt, CMAX);

    const float* kh0 = k + h0*HEAD_DIM + dj;
    const float* vh0 = v + h0*HEAD_DIM + dj;
    const float* kh1 = k + h1*HEAD_DIM + dj;
    const float* vh1 = v + h1*HEAD_DIM + dj;

    // ---- single-pass QK+softmax+AV for BOTH heads (no max subtraction) ----
    float ax0=0.f, ay0=0.f, az0=0.f, aw0=0.f, ps0=0.f;
    float ax1=0.f, ay1=0.f, az1=0.f, aw1=0.f, ps1=0.f;
    #pragma unroll
    for (int i = 0; i < NITER; i++) {
        const int ci  = (i << 3) + grp;
        const int row = s_cand[(ci < nc) ? ci : 0];
        const size_t off = (size_t)row * FEAT;
        const float4 k0 = *(const float4*)(kh0 + off);
        const float4 v0 = *(const float4*)(vh0 + off);
        const float4 k1 = *(const float4*)(kh1 + off);
        const float4 v1 = *(const float4*)(vh1 + off);

        float p0 = q4a.x*k0.x;
        p0 = __builtin_fmaf(q4a.y, k0.y, p0);
        p0 = __builtin_fmaf(q4a.z, k0.z, p0);
        p0 = __builtin_fmaf(q4a.w, k0.w, p0);
        p0 += __shfl_xor(p0, 1);
        p0 += __shfl_xor(p0, 2);
        p0 += __shfl_xor(p0, 4);            // full dot, identical across 8-group

        float p1 = q4b.x*k1.x;
        p1 = __builtin_fmaf(q4b.y, k1.y, p1);
        p1 = __builtin_fmaf(q4b.z, k1.z, p1);
        p1 = __builtin_fmaf(q4b.w, k1.w, p1);
        p1 += __shfl_xor(p1, 1);
        p1 += __shfl_xor(p1, 2);
        p1 += __shfl_xor(p1, 4);

        const bool live = (ci < nc);
        const float e0 = live ? __expf(p0 * 0.17677669529663687f) : 0.0f;
        const float e1 = live ? __expf(p1 * 0.17677669529663687f) : 0.0f;
        ps0 += e0;
        ax0 = __builtin_fmaf(e0, v0.x, ax0);
        ay0 = __builtin_fmaf(e0, v0.y, ay0);
        az0 = __builtin_fmaf(e0, v0.z, az0);
        aw0 = __builtin_fmaf(e0, v0.w, aw0);
        ps1 += e1;
        ax1 = __builtin_fmaf(e1, v1.x, ax1);
        ay1 = __builtin_fmaf(e1, v1.y, ay1);
        az1 = __builtin_fmaf(e1, v1.z, az1);
        aw1 = __builtin_fmaf(e1, v1.w, aw1);
    }

    // ---- reduce over the 8 candidate groups (bits 3..5 of lane) ----
    #pragma unroll
    for (int o = 8; o <= 32; o <<= 1) {
        ax0 += __shfl_xor(ax0, o);
        ay0 += __shfl_xor(ay0, o);
        az0 += __shfl_xor(az0, o);
        aw0 += __shfl_xor(aw0, o);
        ps0 += __shfl_xor(ps0, o);
        ax1 += __shfl_xor(ax1, o);
        ay1 += __shfl_xor(ay1, o);
        az1 += __shfl_xor(az1, o);
        aw1 += __shfl_xor(aw1, o);
        ps1 += __shfl_xor(ps1, o);
    }

    if (lane < 8) {
        float4 r0, r1;
        if (nc > 0) {
            r0.x = ax0/ps0; r0.y = ay0/ps0; r0.z = az0/ps0; r0.w = aw0/ps0;
            r1.x = ax1/ps1; r1.y = ay1/ps1; r1.z = az1/ps1; r1.w = aw1/ps1;
        } else {
            r0.x = r0.y = r0.z = r0.w = 0.0f;
            r1.x = r1.y = r1.z = r1.w = 0.0f;
        }
        *(float4*)(out + l*FEAT + h0*HEAD_DIM + dj) = r0;
        *(float4*)(out + l*FEAT + h1*HEAD_DIM + dj) = r1;
    }
}

extern "C" void kernel_launch(void* const* d_in, const int* in_sizes, int n_in,
                              void* d_out, int out_size, void* d_ws, size_t ws_size,
                              hipStream_t stream) {
    const float* q  = (const float*)d_in[0];
    const float* k  = (const float*)d_in[1];
    const float* v  = (const float*)d_in[2];
    const float* K0 = (const float*)d_in[3];
    const float* K1 = (const float*)d_in[4];
    const float* R  = (const float*)d_in[5];
    const float* t  = (const float*)d_in[6];
    float* out = (float*)d_out;
    (void)d_ws; (void)ws_size;
    one2many_fused<<<NPIX, 256, 0, stream>>>(q, k, v, K0, K1, R, t, out);
}